// Round 4
// baseline (144.250 us; speedup 1.0000x reference)
//
#include <hip/hip_runtime.h>
#include <hip/hip_bf16.h>
#include <cmath>

typedef __bf16 bf16_t;
typedef __attribute__((ext_vector_type(4)))  __bf16 bf16x4;
typedef __attribute__((ext_vector_type(8)))  __bf16 bf16x8;
typedef __attribute__((ext_vector_type(16))) float  f32x16;
typedef __attribute__((ext_vector_type(4)))  float  f32x4;

#define HW    65536
#define BNC   8            // B * NUM_CHANS
#define CH    128          // gram chunks per bnc   (chunk = 512 px)
#define APB   64           // apply blocks per bnc  (block = 1024 px)
#define FN    65536.0f
#define REPS  1e-12f

__device__ __forceinline__ bf16_t tob(float x){ return (bf16_t)x; }

// ---------------- Kernel A: partial channel-gram G (32x32) + channel sums ----------------
// Tile 32ch x 512px staged to LDS (coalesced 1KiB global reads), rows padded to
// 1040B (65 x 16B, odd) so the 32-row ds_read_b128 fragment fetch is conflict-free.
// A and B fragments are the SAME data -> correct for any hardware k-permutation.
__global__ __launch_bounds__(256) void k_gram(const float* __restrict__ x,
                                              float* __restrict__ P,
                                              float* __restrict__ PS)
{
    __shared__ float smemf[8320];               // 33280 B, overlaid: bf16 tile | red
    __shared__ float sxl[32];
    bf16_t (*tile)[520] = (bf16_t (*)[520])smemf;
    float  (*red)[1024] = (float  (*)[1024])smemf;

    const int bid   = blockIdx.x;
    const int bnc   = bid >> 7;
    const int chunk = bid & (CH - 1);
    const int tid   = threadIdx.x;
    const int lane  = tid & 63;
    const int wv    = tid >> 6;
    const int ch    = lane & 31;
    const int hi    = lane >> 5;

    if (tid < 32) sxl[tid] = 0.0f;
    __syncthreads();

    // ---- stage: coalesced f32x4 loads (64 lanes x 16B = 1KiB contiguous) ----
    const float* xb = x + (size_t)bnc * 32 * HW + chunk * 512;
    #pragma unroll
    for (int it = 0; it < 16; ++it) {
        int i   = tid + 256 * it;
        int row = i >> 7;                 // 128 f32x4 per 512-px row
        int c4  = i & 127;
        f32x4 v = *(const f32x4*)(xb + (size_t)row * HW + c4 * 4);
        bf16x4 b;
        b[0] = tob(v.x); b[1] = tob(v.y); b[2] = tob(v.z); b[3] = tob(v.w);
        *(bf16x4*)&tile[row][c4 * 4] = b;
    }
    __syncthreads();

    // ---- channel sums from the staged tile (2-way LDS aliasing only) ----
    {
        int sch = tid >> 3, seg = tid & 7;
        float s = 0.0f;
        #pragma unroll
        for (int k8 = 0; k8 < 8; ++k8) {
            bf16x8 u = *(const bf16x8*)&tile[sch][seg * 64 + k8 * 8];
            #pragma unroll
            for (int j = 0; j < 8; ++j) s += (float)u[j];
        }
        atomicAdd(&sxl[sch], s);
    }

    // ---- MFMA: G += X X^T over this wave's 128-px window ----
    f32x16 acc;
    #pragma unroll
    for (int r = 0; r < 16; ++r) acc[r] = 0.0f;
    #pragma unroll
    for (int s8 = 0; s8 < 8; ++s8) {
        int px = wv * 128 + s8 * 16 + 8 * hi;
        bf16x8 f = *(const bf16x8*)&tile[ch][px];      // conflict-free b128
        acc = __builtin_amdgcn_mfma_f32_32x32x16_bf16(f, f, acc, 0, 0, 0);
    }
    __syncthreads();                                   // tile reads done

    // ---- cross-wave reduce via LDS overlay, write partials ----
    #pragma unroll
    for (int r = 0; r < 16; ++r) {
        int row = (r & 3) + 8 * (r >> 2) + 4 * hi;     // verified C/D layout
        red[wv][row * 32 + ch] = acc[r];
    }
    __syncthreads();

    float* Pp = P + (size_t)bid * 1024;
    #pragma unroll
    for (int i = 0; i < 4; ++i) {
        int e = tid + 256 * i;
        Pp[e] = red[0][e] + red[1][e] + red[2][e] + red[3][e];
    }
    if (tid < 32) PS[bid * 32 + tid] = sxl[tid];
}

// ---------------- Kernel B: reduce partials, attention algebra, emit MT, K0 ----------
// out[b, nc*32+d, n] = K0[d] + sum_e MT[e][d] * x[b, nc*32+e, n]
__global__ __launch_bounds__(1024) void k_attn(const float* __restrict__ P,
                                               const float* __restrict__ PS,
                                               const float* __restrict__ w_qkv,
                                               const float* __restrict__ b_qkv,
                                               const float* __restrict__ w_fus,
                                               const float* __restrict__ b_fus,
                                               const float* __restrict__ tin,
                                               float* __restrict__ MT,
                                               float* __restrict__ K0)
{
    const int bnc = blockIdx.x;          // 8 blocks
    const int nc  = bnc & 3;
    const int tid = threadIdx.x;

    __shared__ float G[1024];
    __shared__ float Sx[32];

    {
        float g = 0.0f;
        const float* Pp = P + (size_t)bnc * CH * 1024;
        for (int c = 0; c < CH; ++c) g += Pp[c * 1024 + tid];
        G[tid] = g;
        if (tid < 32) {
            float s = 0.0f;
            const float* Sp = PS + bnc * CH * 32;
            for (int c = 0; c < CH; ++c) s += Sp[c * 32 + tid];
            Sx[tid] = s;
        }
    }
    __syncthreads();

    const int d = tid >> 5, j = tid & 31;
    const int cd = nc * 32 + d, cj = nc * 32 + j;
    const float Gdj = G[d * 32 + j], Gdd = G[d * 33], Gjj = G[j * 33];
    const float Sxd = Sx[d], Sxj = Sx[j];

    float mloc = 0.0f, kloc = 0.0f;
    #pragma unroll
    for (int e = 0; e < 2; ++e) {
        float aq = w_qkv[cd * 6 + e],     cq = b_qkv[cd * 6 + e];
        float ak = w_qkv[cj * 6 + 2 + e], ck = b_qkv[cj * 6 + 2 + e];
        float av = w_qkv[cj * 6 + 4 + e], cv = b_qkv[cj * 6 + 4 + e];
        float wf = w_fus[cd * 2 + e];
        float tv = tin[e * 4 + nc];

        float S  = aq * ak * Gdj + aq * ck * Sxd + cq * ak * Sxj + cq * ck * FN;
        float Nq = aq * aq * Gdd + 2.0f * aq * cq * Sxd + cq * cq * FN;
        float Nk = ak * ak * Gjj + 2.0f * ak * ck * Sxj + ck * ck * FN;
        float pre = S / (fmaxf(sqrtf(Nq), REPS) * fmaxf(sqrtf(Nk), REPS)) * tv;

        float mx = pre;
        #pragma unroll
        for (int o = 16; o; o >>= 1) mx = fmaxf(mx, __shfl_xor(mx, o));
        float p = expf(pre - mx);
        float sm = p;
        #pragma unroll
        for (int o = 16; o; o >>= 1) sm += __shfl_xor(sm, o);
        float A = p / sm;

        mloc += wf * A * av;
        kloc += wf * A * cv;
    }
    MT[bnc * 1024 + j * 32 + d] = mloc;                 // transposed for k_apply
    float kr = kloc;
    #pragma unroll
    for (int o = 16; o; o >>= 1) kr += __shfl_xor(kr, o);
    if (j == 0) K0[bnc * 32 + d] = b_fus[cd] + kr;
}

// ---------------- Kernel C: out = M * x + K0, pure-VALU, float4 pixels -------------------
// Each thread owns 4 consecutive pixels: 1KiB-coalesced loads AND stores; M via s_loads.
__global__ __launch_bounds__(256) void k_apply(const float* __restrict__ x,
                                               const float* __restrict__ MT,
                                               const float* __restrict__ K0,
                                               float* __restrict__ out)
{
    const int bnc = blockIdx.x >> 6;          // / APB
    const int blk = blockIdx.x & (APB - 1);
    const int p   = blk * 1024 + threadIdx.x * 4;

    const float* xb = x   + (size_t)bnc * 32 * HW + p;
    float*       ob = out + (size_t)bnc * 32 * HW + p;
    const float* Mb = MT  + bnc * 1024;       // MT[e][d], wave-uniform -> s_load
    const float* Kb = K0  + bnc * 32;

    f32x4 acc[32];
    const f32x4 zz = {0.0f, 0.0f, 0.0f, 0.0f};
    #pragma unroll
    for (int d = 0; d < 32; ++d) acc[d] = zz;

    #pragma unroll 4
    for (int e = 0; e < 32; ++e) {
        f32x4 xv = *(const f32x4*)(xb + (size_t)e * HW);
        #pragma unroll
        for (int d = 0; d < 32; ++d) {
            acc[d] += xv * Mb[e * 32 + d];
        }
    }

    #pragma unroll
    for (int d = 0; d < 32; ++d) {
        f32x4 r = acc[d] + Kb[d];
        *(f32x4*)(ob + (size_t)d * HW) = r;
    }
}

// -------------------------------------------------------------------------------------------
extern "C" void kernel_launch(void* const* d_in, const int* in_sizes, int n_in,
                              void* d_out, int out_size, void* d_ws, size_t ws_size,
                              hipStream_t stream)
{
    (void)in_sizes; (void)n_in; (void)out_size;
    const float* x      = (const float*)d_in[0];
    const float* w_qkv  = (const float*)d_in[1];
    const float* b_qkv  = (const float*)d_in[2];
    const float* w_fus  = (const float*)d_in[3];
    const float* b_fus  = (const float*)d_in[4];
    const float* tin    = (const float*)d_in[5];
    float* out = (float*)d_out;

    // ws layout: [MT (8*1024)][K0 (8*32)][P (8*CH*1024)][PS (8*CH*32)]
    float* Mbuf  = (float*)d_ws;
    float* K0buf = Mbuf + BNC * 1024;
    const size_t small  = (size_t)(BNC * 1024 + BNC * 32);
    const size_t needP  = (size_t)BNC * CH * 1024;
    const size_t needPS = (size_t)BNC * CH * 32;
    float *P, *PS;
    if (ws_size >= (small + needP + needPS) * sizeof(float)) {
        P  = K0buf + BNC * 32;
        PS = P + needP;
    } else {
        // fall back: use d_out as scratch; k_apply fully overwrites it afterwards.
        P  = out;
        PS = out + needP;
    }

    k_gram <<<BNC * CH,  256,  0, stream>>>(x, P, PS);
    k_attn <<<BNC,       1024, 0, stream>>>(P, PS, w_qkv, b_qkv, w_fus, b_fus, tin,
                                            Mbuf, K0buf);
    k_apply<<<BNC * APB, 256,  0, stream>>>(x, Mbuf, K0buf, out);
}